// Round 13
// baseline (62.809 us; speedup 1.0000x reference)
//
#include <hip/hip_runtime.h>

typedef unsigned short u16;
typedef unsigned int   u32;
typedef short s8v  __attribute__((ext_vector_type(8)));   // 8 bf16 (4 VGPR)
typedef float f16v __attribute__((ext_vector_type(16)));  // 32x32 acc
typedef unsigned int u32x4 __attribute__((ext_vector_type(4)));
typedef float f4 __attribute__((ext_vector_type(4)));

#define CHUNKB 4128                   // 258 slots * 16 B (one c-chunk of a row)
#define RB2    16512                  // 4 chunks per staged row
#define SROWS  6                      // 4 output rows + 2 halo
#define LDS_BYTES (SROWS * RB2)       // 99072 -> 1 block/CU

__device__ inline u16 f2bf(float f) {
    u32 u = __builtin_bit_cast(u32, f);
    u += 0x7FFFu + ((u >> 16) & 1u);   // RNE; inputs finite
    return (u16)(u >> 16);
}
__device__ inline u32 pk2(float lo, float hi) {
    return (u32)f2bf(lo) | ((u32)f2bf(hi) << 16);
}

// Full-row fused conv: block owns 32o x 256px x 4h. Staging reads are 1KB
// contiguous float4 row-streams (copy-bench pattern); rows of one channel are
// page-sequential. No w-halo (image edge = true zero pad). LDS slot swizzle
// ps^((ps>>4)&7) (write & read sides) spreads the per-px u32 transpose writes.
// 512 thr = 8 waves; stage: wave=(chunk,row-par); compute: wave=(row,px-half).
// Grid: 16n*64hb = 1024, XCD-swizzled so vertical neighbors share an XCD L2.
__global__ __launch_bounds__(512, 1) void k_fused(const float* __restrict__ x,
                                                  const float* __restrict__ wgt,
                                                  const float* __restrict__ bias,
                                                  const float* __restrict__ scale_p,
                                                  float* __restrict__ out) {
    __shared__ __align__(16) char lds[LDS_BYTES];

    const int bid     = blockIdx.x;
    const int logical = ((bid & 7) << 7) | (bid >> 3);   // grid 1024
    const int n  = logical >> 6;
    const int hb = logical & 63;
    const int h0 = hb << 2;
    const int t = threadIdx.x, l = t & 63, wave = t >> 6, g = l >> 5, ln = l & 31;

    // ---- weight repack into LDS overlay: [o][c][9] f32 -> [tap][o*32+c] bf16
    {
        u16* wl = (u16*)lds;
        #pragma unroll
        for (int k = 0; k < 18; ++k) {                   // 9216 = 18*512
            const int idx = t + (k << 9);
            const int tap = idx % 9;
            const int oc  = idx / 9;
            wl[tap * 1024 + oc] = f2bf(wgt[idx]);
        }
    }
    __syncthreads();

    s8v A[9][2];
    {
        const u16* wl = (const u16*)lds;
        #pragma unroll
        for (int tap = 0; tap < 9; ++tap)
            #pragma unroll
            for (int q = 0; q < 2; ++q)
                A[tap][q] = *(const s8v*)(wl + tap * 1024 + ln * 32 + q * 16 + g * 8);
    }
    const float scale = scale_p[0];
    float bias_r[16];
    #pragma unroll
    for (int rg = 0; rg < 16; ++rg) bias_r[rg] = bias[(rg & 3) + 8 * (rg >> 2) + 4 * g];
    __syncthreads();   // overlay consumed; LDS free for tile

    const float* xbase = x + ((size_t)n << 21);          // n*32*65536

    // ---- zero boundary columns ps=0 / ps=257 (slots 0 / 257 under swizzle)
    if (t < 48) {
        const int r = t >> 3, q = (t >> 1) & 3, side = t & 1;
        *(u32x4*)(lds + r * RB2 + q * CHUNKB + (side ? 257 : 0) * 16) = u32x4{0, 0, 0, 0};
    }

    // ---- stage: wave=(chunk q, row parity rs); lane l covers px 4l..4l+3.
    // Per c-pair: 3+3 float4 loads (each 1KB contiguous across the wave, rows
    // page-sequential), pk2, 12 swizzled u32 LDS writes.
    {
        const int q  = wave & 3;
        const int rs = wave >> 2;
        const float* cb = xbase + (size_t)(q * 8) * 65536 + 4 * l;
        #pragma unroll
        for (int cp = 0; cp < 4; ++cp) {
            const float* p0 = cb + (size_t)(2 * cp) * 65536;
            const float* p1 = p0 + 65536;
            f4 v0[3], v1[3];
            int hcl[3], bad[3];
            #pragma unroll
            for (int ri = 0; ri < 3; ++ri) {
                const int hin = h0 - 1 + rs + 2 * ri;
                hcl[ri] = hin < 0 ? 0 : (hin > 255 ? 255 : hin);
                bad[ri] = (hin < 0) | (hin > 255);
                v0[ri] = *(const f4*)(p0 + (size_t)hcl[ri] * 256);
            }
            #pragma unroll
            for (int ri = 0; ri < 3; ++ri)
                v1[ri] = *(const f4*)(p1 + (size_t)hcl[ri] * 256);
            #pragma unroll
            for (int ri = 0; ri < 3; ++ri) {
                const int r = rs + 2 * ri;
                char* rb = lds + r * RB2 + q * CHUNKB + cp * 4;
                #pragma unroll
                for (int i = 0; i < 4; ++i) {
                    const int ps   = 4 * l + 1 + i;
                    const int slot = ps ^ ((ps >> 4) & 7);
                    const u32 pk = bad[ri] ? 0u : pk2(v0[ri][i], v1[ri][i]);
                    *(u32*)(rb + slot * 16) = pk;
                }
            }
        }
    }
    __syncthreads();   // the only barrier before compute

    // ---- compute: wave -> output row hr=wave&3, px half ph=wave>>2.
    // One 32x32 (o x px) acc tile at a time: 18 MFMAs, store, next.
    const int hr = wave & 3;
    const int ph = wave >> 2;
    const int h  = h0 + hr;
    #pragma unroll
    for (int pn = 0; pn < 4; ++pn) {
        const int px0 = ph * 128 + pn * 32;

        f16v acc;
        #pragma unroll
        for (int rg = 0; rg < 16; ++rg) acc[rg] = 0.f;

        #pragma unroll
        for (int kh = 0; kh < 3; ++kh) {
            const char* rb = lds + (hr + kh) * RB2 + g * CHUNKB;
            #pragma unroll
            for (int kw = 0; kw < 3; ++kw) {
                const int ps   = px0 + ln + kw;          // px = px0+ln+kw-1
                const int slot = ps ^ ((ps >> 4) & 7);
                const int tap  = kh * 3 + kw;
                #pragma unroll
                for (int q2 = 0; q2 < 2; ++q2) {
                    const s8v b = *(const s8v*)(rb + q2 * 2 * CHUNKB + slot * 16);
                    acc = __builtin_amdgcn_mfma_f32_32x32x16_bf16(A[tap][q2], b, acc, 0, 0, 0);
                }
            }
        }

        float* op = out + ((size_t)n << 21) + (size_t)h * 256 + px0 + ln;
        #pragma unroll
        for (int rg = 0; rg < 16; ++rg) {
            const int o = (rg & 3) + 8 * (rg >> 2) + 4 * g;
            op[(size_t)o * 65536] = scale * acc[rg] + bias_r[rg];
        }
    }
}

extern "C" void kernel_launch(void* const* d_in, const int* in_sizes, int n_in,
                              void* d_out, int out_size, void* d_ws, size_t ws_size,
                              hipStream_t stream) {
    const float* x     = (const float*)d_in[0];
    const float* wgt   = (const float*)d_in[1];
    const float* bias  = (const float*)d_in[2];
    const float* scale = (const float*)d_in[3];
    float* out = (float*)d_out;
    k_fused<<<dim3(1024), dim3(512), 0, stream>>>(x, wgt, bias, scale, out);
}